// Round 2
// baseline (269.770 us; speedup 1.0000x reference)
//
#include <hip/hip_runtime.h>

// Problem constants (fixed by the reference)
#define T_TOKENS 16384   // B*S = 4*4096
#define HDIM     2048
#define NEXP     8
#define TPW      2                               // tokens per wave (8 caused spill @210us)
#define WAVES_PER_BLOCK 16                       // 1024-thread blocks
#define TOK_PER_BLOCK (WAVES_PER_BLOCK * TPW)    // 32
#define NBLOCKS  (T_TOKENS / TOK_PER_BLOCK)      // 512 -> exactly 2 blocks/CU on 256 CUs

__device__ __forceinline__ float dot4(float4 a, float4 b) {
    return a.x * b.x + a.y * b.y + a.z * b.z + a.w * b.w;
}

// Value-splitting butterfly stage: 2*D live accumulators -> D.
// Starting from acc[16] and running D=8,4,2,1: within each 16-lane group,
// lane l ends holding the group-partial sum of value index (l & 15).
template <int D>
__device__ __forceinline__ void reduce_stage(float* acc, int lane) {
    const bool upper = (lane & D) != 0;
#pragma unroll
    for (int i = 0; i < D; ++i) {
        float send = upper ? acc[i] : acc[i + D];
        float recv = __shfl_xor(send, D, 64);
        float keep = upper ? acc[i + D] : acc[i];
        acc[i] = keep + recv;
    }
}

// __launch_bounds__(1024, 8): 8 waves/EU -> VGPR cap 64 -> 2 blocks/CU
// (32 waves/CU = 100% occupancy; LDS 2x64KB = 128KB <= 160KB).
__global__ __launch_bounds__(1024, 8) void router_fused(
    const float* __restrict__ x, const float* __restrict__ gate_w,
    float* __restrict__ out, int* __restrict__ gcnt, int* __restrict__ flag) {
    __shared__ float lds_gate[NEXP * HDIM];  // 65536 bytes, ONE copy per 16 waves
    __shared__ int   hist[NEXP];

    const int tid = threadIdx.x;
    if (tid < NEXP) hist[tid] = 0;

    // Stage gate_w (8x2048 f32 = 64 KB): 4096 float4 / 1024 threads = 4 each.
    const float4* g4 = (const float4*)gate_w;
    float4* l4 = (float4*)lds_gate;
#pragma unroll
    for (int i = 0; i < (NEXP * HDIM / 4) / 1024; ++i)
        l4[i * 1024 + tid] = g4[i * 1024 + tid];
    __syncthreads();  // also covers hist[] init

    const int lane   = tid & 63;
    const int wave   = tid >> 6;
    const int t_base = (blockIdx.x * WAVES_PER_BLOCK + wave) * TPW;  // exact cover

    float acc[TPW * NEXP];  // acc[t*8+e] — 16 VGPRs
#pragma unroll
    for (int v = 0; v < TPW * NEXP; ++v) acc[v] = 0.f;

    const float4* x4  = (const float4*)x;
    const int     row = HDIM / 4;  // 512 float4 per token

    // Chunk = 256 floats of H (64 lanes x float4); 8 chunks cover H=2048.
    // Manual prefetch of chunk c+1 overlaps HBM latency with the FMA block.
    // unroll 2 (NOT full): bounds live VGPRs ~50 < 64 cap -> no scratch.
    float4 xv[TPW], xn[TPW];
#pragma unroll
    for (int t = 0; t < TPW; ++t)
        xv[t] = x4[(size_t)(t_base + t) * row + lane];

#pragma unroll 2
    for (int c = 0; c < HDIM / 256; ++c) {
        if (c + 1 < HDIM / 256) {
#pragma unroll
            for (int t = 0; t < TPW; ++t)
                xn[t] = x4[(size_t)(t_base + t) * row + (c + 1) * 64 + lane];
        }
#pragma unroll
        for (int e = 0; e < NEXP; ++e) {
            float4 gv = l4[e * row + c * 64 + lane];
#pragma unroll
            for (int t = 0; t < TPW; ++t)
                acc[t * NEXP + e] += dot4(xv[t], gv);
        }
#pragma unroll
        for (int t = 0; t < TPW; ++t) xv[t] = xn[t];
    }

    // Cross-lane reduce: 16 values over 64 lanes (bits 0-3), then fold 16/32.
    reduce_stage<8>(acc, lane);
    reduce_stage<4>(acc, lane);
    reduce_stage<2>(acc, lane);
    reduce_stage<1>(acc, lane);
    float v = acc[0];
    v += __shfl_xor(v, 16, 64);
    v += __shfl_xor(v, 32, 64);
    // Lane l holds logit for token t_base + ((l>>3)&1), expert l&7.
    const float logit = v;

    // Gather this token-group's 8 logits (source lane shares bits 3..5).
    const int base = lane & 56;
    float lg[NEXP];
#pragma unroll
    for (int e = 0; e < NEXP; ++e) lg[e] = __shfl(logit, base + e, 64);

    // top-2, lowest index wins ties (matches jax.lax.top_k)
    int i1 = 0; float m1 = lg[0];
#pragma unroll
    for (int e = 1; e < NEXP; ++e) {
        if (lg[e] > m1) { m1 = lg[e]; i1 = e; }
    }
    int i2 = 1; float m2 = -3.4e38f;
#pragma unroll
    for (int e = 0; e < NEXP; ++e) {
        if (e != i1 && lg[e] > m2) { m2 = lg[e]; i2 = e; }
    }

    // Renormalized softmax over the top-2 (other experts cancel exactly).
    const float r  = __expf(m2 - m1);  // <= 1
    const float w1 = 1.f / (1.f + r);
    const float w2 = 1.f - w1;

    const bool leader = ((lane & 7) == 0) && (lane < 16);  // lanes 0 and 8
    const int  tok    = t_base + (lane >> 3);
    if (leader) {
        out[tok * 2 + 0] = w1;
        out[tok * 2 + 1] = w2;
        out[2 * T_TOKENS + tok * 2 + 0] = (float)i1;  // indices as f32 (flat f32 out)
        out[2 * T_TOKENS + tok * 2 + 1] = (float)i2;
    }

    // Per-wave expert histogram via ballot (only the 2 leader lanes counted),
    // then block-level LDS accumulation -> 8 global atomics per block.
    int my_cnt = 0;
#pragma unroll
    for (int e = 0; e < NEXP; ++e) {
        unsigned long long b1 = __ballot(leader && (i1 == e));
        unsigned long long b2 = __ballot(leader && (i2 == e));
        int c = __popcll(b1) + __popcll(b2);
        if (lane == e) my_cnt = c;
    }
    if (lane < NEXP && my_cnt) atomicAdd(&hist[lane], my_cnt);
    __syncthreads();

    // One thread per block: push histogram, then last-arriving block computes
    // the aux loss (device-scope atomics -> coherent across XCDs).
    if (tid == 0) {
#pragma unroll
        for (int e = 0; e < NEXP; ++e) atomicAdd(&gcnt[e], hist[e]);
        __threadfence();  // counts globally visible before the flag bump
        int old = atomicAdd(flag, 1);
        if (old == NBLOCKS - 1) {
            float m[NEXP];
            float s = 0.f;
#pragma unroll
            for (int e = 0; e < NEXP; ++e) {
                int c = atomicAdd(&gcnt[e], 0);  // atomic RMW read: XCD-coherent
                m[e] = (float)c / (float)T_TOKENS;
                s += m[e];
            }
            const float mean = s / (float)NEXP;
            float var = 0.f;
#pragma unroll
            for (int e = 0; e < NEXP; ++e) {
                float d = m[e] - mean;
                var += d * d;
            }
            var /= (float)(NEXP - 1);        // unbiased (ddof=1), matches torch.var
            out[4 * T_TOKENS] = var * (float)NEXP;
        }
    }
}

extern "C" void kernel_launch(void* const* d_in, const int* in_sizes, int n_in,
                              void* d_out, int out_size, void* d_ws, size_t ws_size,
                              hipStream_t stream) {
    const float* x  = (const float*)d_in[0];
    const float* gw = (const float*)d_in[1];
    float* out = (float*)d_out;
    int* gcnt  = (int*)d_ws;
    int* flag  = gcnt + NEXP;

    hipMemsetAsync(d_ws, 0, 16 * sizeof(int), stream);  // gcnt[8] + flag
    router_fused<<<NBLOCKS, 1024, 0, stream>>>(x, gw, out, gcnt, flag);
}